// Round 7
// baseline (207.851 us; speedup 1.0000x reference)
//
#include <hip/hip_runtime.h>
#include <hip/hip_bf16.h>

#define N_NODES 50000
#define N_EDGES 800000
#define IN_FEAT 128
#define HIDDEN  256
#define OUT_F   64
#define M_PAD   50048   // 782 * 64
#define SCAN_NB 196     // ceil(N_NODES / 256)
#define FILL_T  200704  // 784 blocks * 256 threads; 4 edges/thread

typedef __attribute__((ext_vector_type(8))) short short8;
typedef __attribute__((ext_vector_type(4))) float f32x4;

static __device__ __forceinline__ unsigned short f2bf(float f) {
    unsigned u = __float_as_uint(f);
    unsigned r = (u + 0x7fffu + ((u >> 16) & 1u)) >> 16;   // RNE
    return (unsigned short)r;
}
static __device__ __forceinline__ float bflo(unsigned u) { return __uint_as_float(u << 16); }
static __device__ __forceinline__ float bfhi(unsigned u) { return __uint_as_float(u & 0xffff0000u); }

// ---------------- zero cnt (replaces slow rocclr fillBuffer) ----------------
__global__ __launch_bounds__(256) void zero_k(int* __restrict__ p) {
    int i = blockIdx.x * 256 + threadIdx.x;
    if (i < N_NODES) p[i] = 0;
}

// ---------------- degree count: 4 edges/thread for MLP ----------------
__global__ __launch_bounds__(256) void count_edges_k(const int* __restrict__ dst,
                                                     int* __restrict__ cnt) {
    int t = blockIdx.x * 256 + threadIdx.x;
#pragma unroll
    for (int j = 0; j < 4; j++) {
        int e = t + j * FILL_T;
        if (e < N_EDGES) atomicAdd(&cnt[dst[e]], 1);
    }
}

// ---------------- scan phase A: per-block sums of cnt ----------------
__global__ __launch_bounds__(256) void bsum_k(const int* __restrict__ cnt,
                                              int* __restrict__ bsum) {
    int i = blockIdx.x * 256 + threadIdx.x;
    int v = (i < N_NODES) ? cnt[i] : 0;
#pragma unroll
    for (int m = 1; m < 64; m <<= 1) v += __shfl_xor(v, m);
    __shared__ int ws4[4];
    if ((threadIdx.x & 63) == 0) ws4[threadIdx.x >> 6] = v;
    __syncthreads();
    if (threadIdx.x == 0) bsum[blockIdx.x] = ws4[0] + ws4[1] + ws4[2] + ws4[3];
}

// ---------------- scan phase B: exclusive scan of block sums (1 block) ----------------
__global__ __launch_bounds__(256) void bscan_k(const int* __restrict__ bsum,
                                               int* __restrict__ boff) {
    __shared__ int s[256];
    int t = threadIdx.x;
    int v = (t < SCAN_NB) ? bsum[t] : 0;
    s[t] = v;
    __syncthreads();
    for (int off = 1; off < 256; off <<= 1) {
        int add = (t >= off) ? s[t - off] : 0;
        __syncthreads();
        s[t] += add;
        __syncthreads();
    }
    if (t < SCAN_NB) boff[t] = s[t] - v;   // exclusive
}

// ---------------- scan phase C: per-block exclusive scan + offset -> rowptr ----------------
__global__ __launch_bounds__(256) void rowptr_k(const int* __restrict__ cnt,
                                                const int* __restrict__ boff,
                                                int* __restrict__ rowptr) {
    __shared__ int s[256];
    int t = threadIdx.x;
    int i = blockIdx.x * 256 + t;
    int v = (i < N_NODES) ? cnt[i] : 0;
    s[t] = v;
    __syncthreads();
    for (int off = 1; off < 256; off <<= 1) {
        int add = (t >= off) ? s[t - off] : 0;
        __syncthreads();
        s[t] += add;
        __syncthreads();
    }
    if (i < N_NODES) rowptr[i] = boff[blockIdx.x] + s[t] - v;
    if (blockIdx.x == 0 && t == 0) rowptr[N_NODES] = N_EDGES;
}

// ---------------- CSR fill: cnt doubles as countdown cursor; 4 edges/thread ----------------
__global__ __launch_bounds__(256) void fill_k(const int* __restrict__ src,
                                              const int* __restrict__ dst,
                                              const int* __restrict__ rowptr,
                                              int* __restrict__ cursor,
                                              int* __restrict__ eids) {
    int t = blockIdx.x * 256 + threadIdx.x;
#pragma unroll
    for (int j = 0; j < 4; j++) {
        int e = t + j * FILL_T;
        if (e < N_EDGES) {
            int d = dst[e];
            int old = atomicSub(&cursor[d], 1);        // old in [1..deg]
            eids[rowptr[d] + old - 1] = src[e];
        }
    }
}

// ---------------- convert x -> bf16 into A1[:,128:256] ----------------
__global__ void convert_x_k(const float* __restrict__ x, unsigned int* __restrict__ A1u) {
    int i = blockIdx.x * blockDim.x + threadIdx.x;   // pair index
    if (i >= N_NODES * 64) return;
    int n = i >> 6, p = i & 63;
    float2 v = ((const float2*)(x + (size_t)n * IN_FEAT))[p];
    A1u[(size_t)n * 128 + 64 + p] = (unsigned)f2bf(v.x) | ((unsigned)f2bf(v.y) << 16);
}

// ---------------- W1 -> MFMA fragment layout Wf1[ks][nt][lane][8] (bf16) ----------------
__global__ void convert_w1_k(const float* __restrict__ W1l, const float* __restrict__ W1r,
                             unsigned int* __restrict__ Wf) {
    int i = blockIdx.x * blockDim.x + threadIdx.x;   // 32768 u32
    if (i >= 32768) return;
    int s = i * 2;
    int j = s & 7, lane = (s >> 3) & 63, nt = (s >> 9) & 15, ks = s >> 13;
    int n = nt * 16 + (lane & 15);
    int k = ks * 32 + ((lane >> 4) << 3) + j;
    float v0, v1;
    if (k < 128) { v0 = W1l[n * 128 + k];       v1 = W1l[n * 128 + k + 1]; }
    else         { v0 = W1r[n * 128 + k - 128]; v1 = W1r[n * 128 + k - 127]; }
    Wf[i] = (unsigned)f2bf(v0) | ((unsigned)f2bf(v1) << 16);
}

// ---------------- W2 -> fragment layout Wf2[ks][nt][lane][8] ----------------
__global__ void convert_w2_k(const float* __restrict__ W2l, const float* __restrict__ W2r,
                             unsigned int* __restrict__ Wf) {
    int i = blockIdx.x * blockDim.x + threadIdx.x;   // 16384 u32
    if (i >= 16384) return;
    int s = i * 2;
    int j = s & 7, lane = (s >> 3) & 63, nt = (s >> 9) & 7, ks = s >> 12;
    int n = nt * 16 + (lane & 15);
    int k = ks * 32 + ((lane >> 4) << 3) + j;
    float v0, v1;
    if (n < 64) { v0 = W2l[n * 256 + k];        v1 = W2l[n * 256 + k + 1]; }
    else        { v0 = W2r[(n - 64) * 256 + k]; v1 = W2r[(n - 64) * 256 + k + 1]; }
    Wf[i] = (unsigned)f2bf(v0) | ((unsigned)f2bf(v1) << 16);
}

// ---------------- gather-mean layer 1: 4 edges/iter, dwordx4 per lane ----------------
__global__ void gather1_k(const unsigned int* __restrict__ Au, const int* __restrict__ eids,
                          const int* __restrict__ rowptr, unsigned int* __restrict__ Aw) {
    int w = threadIdx.x >> 6, lane = threadIdx.x & 63;
    int node = blockIdx.x * 4 + w;
    if (node >= N_NODES) return;
    int b = rowptr[node], e = rowptr[node + 1];
    int eg = lane >> 4, cq = lane & 15;
    float a0 = 0.f, a1 = 0.f, a2 = 0.f, a3 = 0.f, a4 = 0.f, a5 = 0.f, a6 = 0.f, a7 = 0.f;
    for (int i = b + eg; i < e; i += 4) {
        int s = eids[i];
        uint4 v = ((const uint4*)(Au + (size_t)s * 128 + 64))[cq];
        a0 += bflo(v.x); a1 += bfhi(v.x);
        a2 += bflo(v.y); a3 += bfhi(v.y);
        a4 += bflo(v.z); a5 += bfhi(v.z);
        a6 += bflo(v.w); a7 += bfhi(v.w);
    }
#pragma unroll
    for (int m = 16; m <= 32; m <<= 1) {
        a0 += __shfl_xor(a0, m); a1 += __shfl_xor(a1, m);
        a2 += __shfl_xor(a2, m); a3 += __shfl_xor(a3, m);
        a4 += __shfl_xor(a4, m); a5 += __shfl_xor(a5, m);
        a6 += __shfl_xor(a6, m); a7 += __shfl_xor(a7, m);
    }
    if (eg == 0) {
        int deg = e - b; if (deg < 1) deg = 1;
        float inv = 1.f / (float)deg;
        uint4 r;
        r.x = (unsigned)f2bf(a0 * inv) | ((unsigned)f2bf(a1 * inv) << 16);
        r.y = (unsigned)f2bf(a2 * inv) | ((unsigned)f2bf(a3 * inv) << 16);
        r.z = (unsigned)f2bf(a4 * inv) | ((unsigned)f2bf(a5 * inv) << 16);
        r.w = (unsigned)f2bf(a6 * inv) | ((unsigned)f2bf(a7 * inv) << 16);
        ((uint4*)(Aw + (size_t)node * 128))[cq] = r;
    }
}

// ---------------- MFMA GEMM1: h = relu(A1 @ W1cat^T + b1), M=M_PAD N=256 K=256 ----------------
__global__ __launch_bounds__(256) void mfma_gemm1_k(
        const unsigned short* __restrict__ A, const unsigned short* __restrict__ Wf,
        const float* __restrict__ b1, unsigned short* __restrict__ h) {
    int wv = threadIdx.x >> 6, lane = threadIdx.x & 63;
    int rowh = wv >> 1, colh = wv & 1;
    int m0 = blockIdx.x * 64 + rowh * 32;
    int row = lane & 15, kg = lane >> 4;
    const short8* Wf8 = (const short8*)Wf;

    short8 af[2][8];
#pragma unroll
    for (int mt = 0; mt < 2; mt++) {
        const short8* ar = (const short8*)(A + (size_t)(m0 + mt * 16 + row) * 256 + kg * 8);
#pragma unroll
        for (int ks = 0; ks < 8; ks++) af[mt][ks] = ar[ks * 4];
    }
    f32x4 acc[2][8];
#pragma unroll
    for (int mt = 0; mt < 2; mt++)
#pragma unroll
        for (int nt = 0; nt < 8; nt++) acc[mt][nt] = (f32x4)(0.f);

#pragma unroll
    for (int ks = 0; ks < 8; ks++) {
        short8 bf[8];
#pragma unroll
        for (int nt = 0; nt < 8; nt++)
            bf[nt] = Wf8[(ks * 16 + colh * 8 + nt) * 64 + lane];
#pragma unroll
        for (int nt = 0; nt < 8; nt++) {
#pragma unroll
            for (int mt = 0; mt < 2; mt++)
                acc[mt][nt] = __builtin_amdgcn_mfma_f32_16x16x32_bf16(af[mt][ks], bf[nt],
                                                                      acc[mt][nt], 0, 0, 0);
        }
    }

#pragma unroll
    for (int mt = 0; mt < 2; mt++) {
        int r0 = m0 + mt * 16 + kg * 4;
#pragma unroll
        for (int nt = 0; nt < 8; nt++) {
            int c = colh * 128 + nt * 16 + row;
            float bias = b1[c];
#pragma unroll
            for (int i = 0; i < 4; i++) {
                float v = acc[mt][nt][i] + bias;
                v = v > 0.f ? v : 0.f;
                h[(size_t)(r0 + i) * 256 + c] = f2bf(v);
            }
        }
    }
}

// ---------------- MFMA GEMM2: [y | out_r] = h @ W2cat^T, M=M_PAD N=128 K=256 ----------------
__global__ __launch_bounds__(256) void mfma_gemm2_k(
        const unsigned short* __restrict__ A, const unsigned short* __restrict__ Wf,
        const float* __restrict__ b2, unsigned short* __restrict__ y,
        float* __restrict__ out) {
    int wv = threadIdx.x >> 6, lane = threadIdx.x & 63;
    int m0 = blockIdx.x * 128 + wv * 32;
    int row = lane & 15, kg = lane >> 4;
    const short8* Wf8 = (const short8*)Wf;

    short8 af[2][8];
#pragma unroll
    for (int mt = 0; mt < 2; mt++) {
        const short8* ar = (const short8*)(A + (size_t)(m0 + mt * 16 + row) * 256 + kg * 8);
#pragma unroll
        for (int ks = 0; ks < 8; ks++) af[mt][ks] = ar[ks * 4];
    }
    f32x4 acc[2][8];
#pragma unroll
    for (int mt = 0; mt < 2; mt++)
#pragma unroll
        for (int nt = 0; nt < 8; nt++) acc[mt][nt] = (f32x4)(0.f);

#pragma unroll
    for (int ks = 0; ks < 8; ks++) {
        short8 bf[8];
#pragma unroll
        for (int nt = 0; nt < 8; nt++)
            bf[nt] = Wf8[(ks * 8 + nt) * 64 + lane];
#pragma unroll
        for (int nt = 0; nt < 8; nt++) {
#pragma unroll
            for (int mt = 0; mt < 2; mt++)
                acc[mt][nt] = __builtin_amdgcn_mfma_f32_16x16x32_bf16(af[mt][ks], bf[nt],
                                                                      acc[mt][nt], 0, 0, 0);
        }
    }

#pragma unroll
    for (int mt = 0; mt < 2; mt++) {
        int r0 = m0 + mt * 16 + kg * 4;
#pragma unroll
        for (int nt = 0; nt < 8; nt++) {
            int c = nt * 16 + row;   // 0..127
#pragma unroll
            for (int i = 0; i < 4; i++) {
                int rr = r0 + i;
                if (nt < 4) {
                    y[(size_t)rr * OUT_F + c] = f2bf(acc[mt][nt][i]);
                } else if (rr < N_NODES) {
                    out[(size_t)rr * OUT_F + (c - 64)] = acc[mt][nt][i] + b2[c - 64];
                }
            }
        }
    }
}

// ---------------- gather-mean layer 2: 8 edges/iter, dwordx4 per lane ----------------
__global__ void gather2_k(const unsigned int* __restrict__ yu, const int* __restrict__ eids,
                          const int* __restrict__ rowptr, float* __restrict__ out) {
    int w = threadIdx.x >> 6, lane = threadIdx.x & 63;
    int node = blockIdx.x * 4 + w;
    if (node >= N_NODES) return;
    int b = rowptr[node], e = rowptr[node + 1];
    int eg = lane >> 3, cq = lane & 7;
    float a0 = 0.f, a1 = 0.f, a2 = 0.f, a3 = 0.f, a4 = 0.f, a5 = 0.f, a6 = 0.f, a7 = 0.f;
    for (int i = b + eg; i < e; i += 8) {
        int s = eids[i];
        uint4 v = ((const uint4*)(yu + (size_t)s * 32))[cq];
        a0 += bflo(v.x); a1 += bfhi(v.x);
        a2 += bflo(v.y); a3 += bfhi(v.y);
        a4 += bflo(v.z); a5 += bfhi(v.z);
        a6 += bflo(v.w); a7 += bfhi(v.w);
    }
#pragma unroll
    for (int m = 8; m <= 32; m <<= 1) {
        a0 += __shfl_xor(a0, m); a1 += __shfl_xor(a1, m);
        a2 += __shfl_xor(a2, m); a3 += __shfl_xor(a3, m);
        a4 += __shfl_xor(a4, m); a5 += __shfl_xor(a5, m);
        a6 += __shfl_xor(a6, m); a7 += __shfl_xor(a7, m);
    }
    if (eg == 0) {
        int deg = e - b; if (deg < 1) deg = 1;
        float inv = 1.f / (float)deg;
        float4* p = (float4*)(out + (size_t)node * OUT_F + cq * 8);
        float4 c0 = p[0], c1 = p[1];
        c0.x += a0 * inv; c0.y += a1 * inv; c0.z += a2 * inv; c0.w += a3 * inv;
        c1.x += a4 * inv; c1.y += a5 * inv; c1.z += a6 * inv; c1.w += a7 * inv;
        p[0] = c0; p[1] = c1;
    }
}

extern "C" void kernel_launch(void* const* d_in, const int* in_sizes, int n_in,
                              void* d_out, int out_size, void* d_ws, size_t ws_size,
                              hipStream_t stream) {
    const float* x    = (const float*)d_in[0];
    const int*   eidx = (const int*)d_in[1];
    const float* W1l  = (const float*)d_in[2];
    const float* W1r  = (const float*)d_in[3];
    const float* b1   = (const float*)d_in[4];
    const float* W2l  = (const float*)d_in[5];
    const float* W2r  = (const float*)d_in[6];
    const float* b2   = (const float*)d_in[7];
    float* out = (float*)d_out;

    const int* src = eidx;             // edge_index[0]
    const int* dst = eidx + N_EDGES;   // edge_index[1]

    // workspace layout (ushort units)
    unsigned short* A1   = (unsigned short*)d_ws;              // [M_PAD][256] bf16
    unsigned short* hbuf = A1 + (size_t)M_PAD * 256;           // [M_PAD][256] bf16
    unsigned short* ybuf = hbuf + (size_t)M_PAD * 256;         // [M_PAD][64]  bf16
    unsigned short* W1f  = ybuf + (size_t)M_PAD * OUT_F;       // 65536 (frag layout)
    unsigned short* W2f  = W1f + 65536;                        // 32768 (frag layout)
    int* cnt    = (int*)(W2f + 32768);            // doubles as fill cursor
    int* rowptr = cnt + N_NODES;                  // 50001
    int* eids   = rowptr + N_NODES + 1;           // 800000
    int* bsum   = eids + N_EDGES;                 // 196
    int* boff   = bsum + SCAN_NB;                 // 196

    // conversions (x -> bf16, weights -> MFMA fragment layout)
    zero_k<<<SCAN_NB, 256, 0, stream>>>(cnt);
    convert_x_k<<<(N_NODES * 64 + 255) / 256, 256, 0, stream>>>(x, (unsigned int*)A1);
    convert_w1_k<<<128, 256, 0, stream>>>(W1l, W1r, (unsigned int*)W1f);
    convert_w2_k<<<64, 256, 0, stream>>>(W2l, W2r, (unsigned int*)W2f);

    // CSR build (3-phase device-wide scan; cnt consumed as cursor by fill_k)
    count_edges_k<<<784, 256, 0, stream>>>(dst, cnt);
    bsum_k<<<SCAN_NB, 256, 0, stream>>>(cnt, bsum);
    bscan_k<<<1, 256, 0, stream>>>(bsum, boff);
    rowptr_k<<<SCAN_NB, 256, 0, stream>>>(cnt, boff, rowptr);
    fill_k<<<784, 256, 0, stream>>>(src, dst, rowptr, cnt, eids);

    // layer-1 aggregation (gather-mean, 4 edges/iter)
    gather1_k<<<(N_NODES + 3) / 4, 256, 0, stream>>>((const unsigned int*)A1, eids, rowptr,
                                                     (unsigned int*)A1);

    // GEMM1 -> h (bf16)
    mfma_gemm1_k<<<M_PAD / 64, 256, 0, stream>>>(A1, W1f, b1, hbuf);

    // GEMM2 -> y (bf16), out_r + b2 (fp32)
    mfma_gemm2_k<<<M_PAD / 128, 256, 0, stream>>>(hbuf, W2f, b2, ybuf, out);

    // layer-2 aggregation (gather-mean, 8 edges/iter)
    gather2_k<<<(N_NODES + 3) / 4, 256, 0, stream>>>((const unsigned int*)ybuf, eids, rowptr, out);
}

// Round 8
// 171.025 us; speedup vs baseline: 1.2153x; 1.2153x over previous
//
#include <hip/hip_runtime.h>
#include <hip/hip_bf16.h>

#define N_NODES 50000
#define N_EDGES 800000
#define IN_FEAT 128
#define HIDDEN  256
#define OUT_F   64
#define M_PAD   50048   // 782 * 64
#define SCAN_NB 196     // ceil(N_NODES / 256)
#define EDGE_NB 3125    // N_EDGES / 256, 1 edge/thread
#define CONV_NB 12500   // N_NODES*64 / 256

typedef __attribute__((ext_vector_type(8))) short short8;
typedef __attribute__((ext_vector_type(4))) float f32x4;

static __device__ __forceinline__ unsigned short f2bf(float f) {
    unsigned u = __float_as_uint(f);
    unsigned r = (u + 0x7fffu + ((u >> 16) & 1u)) >> 16;   // RNE
    return (unsigned short)r;
}
static __device__ __forceinline__ float bflo(unsigned u) { return __uint_as_float(u << 16); }
static __device__ __forceinline__ float bfhi(unsigned u) { return __uint_as_float(u & 0xffff0000u); }

// ---------------- prep: zero cnt | convert W1 | convert W2 (block-range fused) ----------------
__global__ __launch_bounds__(256) void prep_k(int* __restrict__ cnt,
                                              const float* __restrict__ W1l,
                                              const float* __restrict__ W1r,
                                              unsigned int* __restrict__ Wf1,
                                              const float* __restrict__ W2l,
                                              const float* __restrict__ W2r,
                                              unsigned int* __restrict__ Wf2) {
    int b = blockIdx.x, t = threadIdx.x;
    if (b < SCAN_NB) {
        int i = b * 256 + t;
        if (i < N_NODES) cnt[i] = 0;
    } else if (b < SCAN_NB + 128) {
        int i = (b - SCAN_NB) * 256 + t;          // < 32768 u32
        int s = i * 2;
        int j = s & 7, lane = (s >> 3) & 63, nt = (s >> 9) & 15, ks = s >> 13;
        int n = nt * 16 + (lane & 15);
        int k = ks * 32 + ((lane >> 4) << 3) + j;
        float v0, v1;
        if (k < 128) { v0 = W1l[n * 128 + k];       v1 = W1l[n * 128 + k + 1]; }
        else         { v0 = W1r[n * 128 + k - 128]; v1 = W1r[n * 128 + k - 127]; }
        Wf1[i] = (unsigned)f2bf(v0) | ((unsigned)f2bf(v1) << 16);
    } else {
        int i = (b - SCAN_NB - 128) * 256 + t;    // < 16384 u32
        int s = i * 2;
        int j = s & 7, lane = (s >> 3) & 63, nt = (s >> 9) & 7, ks = s >> 12;
        int n = nt * 16 + (lane & 15);
        int k = ks * 32 + ((lane >> 4) << 3) + j;
        float v0, v1;
        if (n < 64) { v0 = W2l[n * 256 + k];        v1 = W2l[n * 256 + k + 1]; }
        else        { v0 = W2r[(n - 64) * 256 + k]; v1 = W2r[(n - 64) * 256 + k + 1]; }
        Wf2[i] = (unsigned)f2bf(v0) | ((unsigned)f2bf(v1) << 16);
    }
}

// ---------------- rank (atomic count w/ returned rank) | convert_x (fused) ----------------
__global__ __launch_bounds__(256) void rank_convert_k(const int* __restrict__ dst,
                                                      int* __restrict__ cnt,
                                                      int* __restrict__ rank,
                                                      const float* __restrict__ x,
                                                      unsigned int* __restrict__ A1u) {
    int b = blockIdx.x, t = threadIdx.x;
    if (b < EDGE_NB) {
        int e = b * 256 + t;                       // exactly covers N_EDGES
        rank[e] = atomicAdd(&cnt[dst[e]], 1);
    } else {
        int i = (b - EDGE_NB) * 256 + t;           // pair index
        int n = i >> 6, p = i & 63;
        float2 v = ((const float2*)(x + (size_t)n * IN_FEAT))[p];
        A1u[(size_t)n * 128 + 64 + p] = (unsigned)f2bf(v.x) | ((unsigned)f2bf(v.y) << 16);
    }
}

// ---------------- scan phase A: per-block sums of cnt ----------------
__global__ __launch_bounds__(256) void bsum_k(const int* __restrict__ cnt,
                                              int* __restrict__ bsum) {
    int i = blockIdx.x * 256 + threadIdx.x;
    int v = (i < N_NODES) ? cnt[i] : 0;
#pragma unroll
    for (int m = 1; m < 64; m <<= 1) v += __shfl_xor(v, m);
    __shared__ int ws4[4];
    if ((threadIdx.x & 63) == 0) ws4[threadIdx.x >> 6] = v;
    __syncthreads();
    if (threadIdx.x == 0) bsum[blockIdx.x] = ws4[0] + ws4[1] + ws4[2] + ws4[3];
}

// ---------------- scan phase B: exclusive scan of block sums (1 block) ----------------
__global__ __launch_bounds__(256) void bscan_k(const int* __restrict__ bsum,
                                               int* __restrict__ boff) {
    __shared__ int s[256];
    int t = threadIdx.x;
    int v = (t < SCAN_NB) ? bsum[t] : 0;
    s[t] = v;
    __syncthreads();
    for (int off = 1; off < 256; off <<= 1) {
        int add = (t >= off) ? s[t - off] : 0;
        __syncthreads();
        s[t] += add;
        __syncthreads();
    }
    if (t < SCAN_NB) boff[t] = s[t] - v;   // exclusive
}

// ---------------- scan phase C: per-block exclusive scan + offset -> rowptr ----------------
__global__ __launch_bounds__(256) void rowptr_k(const int* __restrict__ cnt,
                                                const int* __restrict__ boff,
                                                int* __restrict__ rowptr) {
    __shared__ int s[256];
    int t = threadIdx.x;
    int i = blockIdx.x * 256 + t;
    int v = (i < N_NODES) ? cnt[i] : 0;
    s[t] = v;
    __syncthreads();
    for (int off = 1; off < 256; off <<= 1) {
        int add = (t >= off) ? s[t - off] : 0;
        __syncthreads();
        s[t] += add;
        __syncthreads();
    }
    if (i < N_NODES) rowptr[i] = boff[blockIdx.x] + s[t] - v;
    if (blockIdx.x == 0 && t == 0) rowptr[N_NODES] = N_EDGES;
}

// ---------------- CSR fill: no atomics (rank precomputed) ----------------
__global__ __launch_bounds__(256) void fill_k(const int* __restrict__ src,
                                              const int* __restrict__ dst,
                                              const int* __restrict__ rowptr,
                                              const int* __restrict__ rank,
                                              int* __restrict__ eids) {
    int e = blockIdx.x * 256 + threadIdx.x;        // exactly covers N_EDGES
    int d = dst[e];
    eids[rowptr[d] + rank[e]] = src[e];
}

// ---------------- gather-mean layer 1: 4 edges/iter, dwordx4 per lane ----------------
__global__ void gather1_k(const unsigned int* __restrict__ Au, const int* __restrict__ eids,
                          const int* __restrict__ rowptr, unsigned int* __restrict__ Aw) {
    int w = threadIdx.x >> 6, lane = threadIdx.x & 63;
    int node = blockIdx.x * 4 + w;
    if (node >= N_NODES) return;
    int b = rowptr[node], e = rowptr[node + 1];
    int eg = lane >> 4, cq = lane & 15;
    float a0 = 0.f, a1 = 0.f, a2 = 0.f, a3 = 0.f, a4 = 0.f, a5 = 0.f, a6 = 0.f, a7 = 0.f;
    for (int i = b + eg; i < e; i += 4) {
        int s = eids[i];
        uint4 v = ((const uint4*)(Au + (size_t)s * 128 + 64))[cq];
        a0 += bflo(v.x); a1 += bfhi(v.x);
        a2 += bflo(v.y); a3 += bfhi(v.y);
        a4 += bflo(v.z); a5 += bfhi(v.z);
        a6 += bflo(v.w); a7 += bfhi(v.w);
    }
#pragma unroll
    for (int m = 16; m <= 32; m <<= 1) {
        a0 += __shfl_xor(a0, m); a1 += __shfl_xor(a1, m);
        a2 += __shfl_xor(a2, m); a3 += __shfl_xor(a3, m);
        a4 += __shfl_xor(a4, m); a5 += __shfl_xor(a5, m);
        a6 += __shfl_xor(a6, m); a7 += __shfl_xor(a7, m);
    }
    if (eg == 0) {
        int deg = e - b; if (deg < 1) deg = 1;
        float inv = 1.f / (float)deg;
        uint4 r;
        r.x = (unsigned)f2bf(a0 * inv) | ((unsigned)f2bf(a1 * inv) << 16);
        r.y = (unsigned)f2bf(a2 * inv) | ((unsigned)f2bf(a3 * inv) << 16);
        r.z = (unsigned)f2bf(a4 * inv) | ((unsigned)f2bf(a5 * inv) << 16);
        r.w = (unsigned)f2bf(a6 * inv) | ((unsigned)f2bf(a7 * inv) << 16);
        ((uint4*)(Aw + (size_t)node * 128))[cq] = r;
    }
}

// ---------------- MFMA GEMM1: h = relu(A1 @ W1cat^T + b1), M=M_PAD N=256 K=256 ----------------
__global__ __launch_bounds__(256) void mfma_gemm1_k(
        const unsigned short* __restrict__ A, const unsigned short* __restrict__ Wf,
        const float* __restrict__ b1, unsigned short* __restrict__ h) {
    int wv = threadIdx.x >> 6, lane = threadIdx.x & 63;
    int rowh = wv >> 1, colh = wv & 1;
    int m0 = blockIdx.x * 64 + rowh * 32;
    int row = lane & 15, kg = lane >> 4;
    const short8* Wf8 = (const short8*)Wf;

    short8 af[2][8];
#pragma unroll
    for (int mt = 0; mt < 2; mt++) {
        const short8* ar = (const short8*)(A + (size_t)(m0 + mt * 16 + row) * 256 + kg * 8);
#pragma unroll
        for (int ks = 0; ks < 8; ks++) af[mt][ks] = ar[ks * 4];
    }
    f32x4 acc[2][8];
#pragma unroll
    for (int mt = 0; mt < 2; mt++)
#pragma unroll
        for (int nt = 0; nt < 8; nt++) acc[mt][nt] = (f32x4)(0.f);

#pragma unroll
    for (int ks = 0; ks < 8; ks++) {
        short8 bf[8];
#pragma unroll
        for (int nt = 0; nt < 8; nt++)
            bf[nt] = Wf8[(ks * 16 + colh * 8 + nt) * 64 + lane];
#pragma unroll
        for (int nt = 0; nt < 8; nt++) {
#pragma unroll
            for (int mt = 0; mt < 2; mt++)
                acc[mt][nt] = __builtin_amdgcn_mfma_f32_16x16x32_bf16(af[mt][ks], bf[nt],
                                                                      acc[mt][nt], 0, 0, 0);
        }
    }

#pragma unroll
    for (int mt = 0; mt < 2; mt++) {
        int r0 = m0 + mt * 16 + kg * 4;
#pragma unroll
        for (int nt = 0; nt < 8; nt++) {
            int c = colh * 128 + nt * 16 + row;
            float bias = b1[c];
#pragma unroll
            for (int i = 0; i < 4; i++) {
                float v = acc[mt][nt][i] + bias;
                v = v > 0.f ? v : 0.f;
                h[(size_t)(r0 + i) * 256 + c] = f2bf(v);
            }
        }
    }
}

// ---------------- MFMA GEMM2: [y | out_r] = h @ W2cat^T, M=M_PAD N=128 K=256 ----------------
__global__ __launch_bounds__(256) void mfma_gemm2_k(
        const unsigned short* __restrict__ A, const unsigned short* __restrict__ Wf,
        const float* __restrict__ b2, unsigned short* __restrict__ y,
        float* __restrict__ out) {
    int wv = threadIdx.x >> 6, lane = threadIdx.x & 63;
    int m0 = blockIdx.x * 128 + wv * 32;
    int row = lane & 15, kg = lane >> 4;
    const short8* Wf8 = (const short8*)Wf;

    short8 af[2][8];
#pragma unroll
    for (int mt = 0; mt < 2; mt++) {
        const short8* ar = (const short8*)(A + (size_t)(m0 + mt * 16 + row) * 256 + kg * 8);
#pragma unroll
        for (int ks = 0; ks < 8; ks++) af[mt][ks] = ar[ks * 4];
    }
    f32x4 acc[2][8];
#pragma unroll
    for (int mt = 0; mt < 2; mt++)
#pragma unroll
        for (int nt = 0; nt < 8; nt++) acc[mt][nt] = (f32x4)(0.f);

#pragma unroll
    for (int ks = 0; ks < 8; ks++) {
        short8 bf[8];
#pragma unroll
        for (int nt = 0; nt < 8; nt++)
            bf[nt] = Wf8[(ks * 8 + nt) * 64 + lane];
#pragma unroll
        for (int nt = 0; nt < 8; nt++) {
#pragma unroll
            for (int mt = 0; mt < 2; mt++)
                acc[mt][nt] = __builtin_amdgcn_mfma_f32_16x16x32_bf16(af[mt][ks], bf[nt],
                                                                      acc[mt][nt], 0, 0, 0);
        }
    }

#pragma unroll
    for (int mt = 0; mt < 2; mt++) {
        int r0 = m0 + mt * 16 + kg * 4;
#pragma unroll
        for (int nt = 0; nt < 8; nt++) {
            int c = nt * 16 + row;   // 0..127
#pragma unroll
            for (int i = 0; i < 4; i++) {
                int rr = r0 + i;
                if (nt < 4) {
                    y[(size_t)rr * OUT_F + c] = f2bf(acc[mt][nt][i]);
                } else if (rr < N_NODES) {
                    out[(size_t)rr * OUT_F + (c - 64)] = acc[mt][nt][i] + b2[c - 64];
                }
            }
        }
    }
}

// ---------------- gather-mean layer 2: 8 edges/iter, dwordx4 per lane ----------------
__global__ void gather2_k(const unsigned int* __restrict__ yu, const int* __restrict__ eids,
                          const int* __restrict__ rowptr, float* __restrict__ out) {
    int w = threadIdx.x >> 6, lane = threadIdx.x & 63;
    int node = blockIdx.x * 4 + w;
    if (node >= N_NODES) return;
    int b = rowptr[node], e = rowptr[node + 1];
    int eg = lane >> 3, cq = lane & 7;
    float a0 = 0.f, a1 = 0.f, a2 = 0.f, a3 = 0.f, a4 = 0.f, a5 = 0.f, a6 = 0.f, a7 = 0.f;
    for (int i = b + eg; i < e; i += 8) {
        int s = eids[i];
        uint4 v = ((const uint4*)(yu + (size_t)s * 32))[cq];
        a0 += bflo(v.x); a1 += bfhi(v.x);
        a2 += bflo(v.y); a3 += bfhi(v.y);
        a4 += bflo(v.z); a5 += bfhi(v.z);
        a6 += bflo(v.w); a7 += bfhi(v.w);
    }
#pragma unroll
    for (int m = 8; m <= 32; m <<= 1) {
        a0 += __shfl_xor(a0, m); a1 += __shfl_xor(a1, m);
        a2 += __shfl_xor(a2, m); a3 += __shfl_xor(a3, m);
        a4 += __shfl_xor(a4, m); a5 += __shfl_xor(a5, m);
        a6 += __shfl_xor(a6, m); a7 += __shfl_xor(a7, m);
    }
    if (eg == 0) {
        int deg = e - b; if (deg < 1) deg = 1;
        float inv = 1.f / (float)deg;
        float4* p = (float4*)(out + (size_t)node * OUT_F + cq * 8);
        float4 c0 = p[0], c1 = p[1];
        c0.x += a0 * inv; c0.y += a1 * inv; c0.z += a2 * inv; c0.w += a3 * inv;
        c1.x += a4 * inv; c1.y += a5 * inv; c1.z += a6 * inv; c1.w += a7 * inv;
        p[0] = c0; p[1] = c1;
    }
}

extern "C" void kernel_launch(void* const* d_in, const int* in_sizes, int n_in,
                              void* d_out, int out_size, void* d_ws, size_t ws_size,
                              hipStream_t stream) {
    const float* x    = (const float*)d_in[0];
    const int*   eidx = (const int*)d_in[1];
    const float* W1l  = (const float*)d_in[2];
    const float* W1r  = (const float*)d_in[3];
    const float* b1   = (const float*)d_in[4];
    const float* W2l  = (const float*)d_in[5];
    const float* W2r  = (const float*)d_in[6];
    const float* b2   = (const float*)d_in[7];
    float* out = (float*)d_out;

    const int* src = eidx;             // edge_index[0]
    const int* dst = eidx + N_EDGES;   // edge_index[1]

    // workspace layout (ushort units)
    unsigned short* A1   = (unsigned short*)d_ws;              // [M_PAD][256] bf16
    unsigned short* hbuf = A1 + (size_t)M_PAD * 256;           // [M_PAD][256] bf16
    unsigned short* ybuf = hbuf + (size_t)M_PAD * 256;         // [M_PAD][64]  bf16
    unsigned short* W1f  = ybuf + (size_t)M_PAD * OUT_F;       // 65536 (frag layout)
    unsigned short* W2f  = W1f + 65536;                        // 32768 (frag layout)
    int* cnt    = (int*)(W2f + 32768);            // 50000
    int* rowptr = cnt + N_NODES;                  // 50001
    int* eids   = rowptr + N_NODES + 1;           // 800000
    int* rank   = eids + N_EDGES;                 // 800000
    int* bsum   = rank + N_EDGES;                 // 196
    int* boff   = bsum + SCAN_NB;                 // 196

    // prep: zero cnt | convert weights to fragment layout
    prep_k<<<SCAN_NB + 128 + 64, 256, 0, stream>>>(cnt, W1l, W1r, (unsigned int*)W1f,
                                                   W2l, W2r, (unsigned int*)W2f);

    // rank (atomic degree count w/ per-edge rank) fused with x->bf16 convert
    rank_convert_k<<<EDGE_NB + CONV_NB, 256, 0, stream>>>(dst, cnt, rank, x,
                                                          (unsigned int*)A1);

    // rowptr scan (3-phase)
    bsum_k<<<SCAN_NB, 256, 0, stream>>>(cnt, bsum);
    bscan_k<<<1, 256, 0, stream>>>(bsum, boff);
    rowptr_k<<<SCAN_NB, 256, 0, stream>>>(cnt, boff, rowptr);

    // CSR fill (atomic-free)
    fill_k<<<EDGE_NB, 256, 0, stream>>>(src, dst, rowptr, rank, eids);

    // layer-1 aggregation (gather-mean, 4 edges/iter)
    gather1_k<<<(N_NODES + 3) / 4, 256, 0, stream>>>((const unsigned int*)A1, eids, rowptr,
                                                     (unsigned int*)A1);

    // GEMM1 -> h (bf16)
    mfma_gemm1_k<<<M_PAD / 64, 256, 0, stream>>>(A1, W1f, b1, hbuf);

    // GEMM2 -> y (bf16), out_r + b2 (fp32)
    mfma_gemm2_k<<<M_PAD / 128, 256, 0, stream>>>(hbuf, W2f, b2, ybuf, out);

    // layer-2 aggregation (gather-mean, 8 edges/iter)
    gather2_k<<<(N_NODES + 3) / 4, 256, 0, stream>>>((const unsigned int*)ybuf, eids, rowptr, out);
}

// Round 9
// 165.856 us; speedup vs baseline: 1.2532x; 1.0312x over previous
//
#include <hip/hip_runtime.h>
#include <hip/hip_bf16.h>

#define N_NODES 50000
#define N_EDGES 800000
#define IN_FEAT 128
#define HIDDEN  256
#define OUT_F   64
#define M_PAD   50048   // 782 * 64
#define SCAN_NB 196     // ceil(N_NODES / 256)
#define RANK_NB 1024    // rank block range
#define CONV_NB 1024    // convert block range
#define FILL_NB 1024
#define GATH_NB 2048
#define NGROUPS 12500   // N_NODES/4 node-groups (4 nodes per 256-thread block)

typedef __attribute__((ext_vector_type(8))) short short8;
typedef __attribute__((ext_vector_type(4))) float f32x4;

static __device__ __forceinline__ unsigned short f2bf(float f) {
    unsigned u = __float_as_uint(f);
    unsigned r = (u + 0x7fffu + ((u >> 16) & 1u)) >> 16;   // RNE
    return (unsigned short)r;
}
static __device__ __forceinline__ float bflo(unsigned u) { return __uint_as_float(u << 16); }
static __device__ __forceinline__ float bfhi(unsigned u) { return __uint_as_float(u & 0xffff0000u); }

// ---------------- prep: zero cnt | convert W1 | convert W2 (block-range fused) ----------------
__global__ __launch_bounds__(256) void prep_k(int* __restrict__ cnt,
                                              const float* __restrict__ W1l,
                                              const float* __restrict__ W1r,
                                              unsigned int* __restrict__ Wf1,
                                              const float* __restrict__ W2l,
                                              const float* __restrict__ W2r,
                                              unsigned int* __restrict__ Wf2) {
    int b = blockIdx.x, t = threadIdx.x;
    if (b < SCAN_NB) {
        int i = b * 256 + t;
        if (i < N_NODES) cnt[i] = 0;
    } else if (b < SCAN_NB + 128) {
        int i = (b - SCAN_NB) * 256 + t;          // < 32768 u32
        int s = i * 2;
        int j = s & 7, lane = (s >> 3) & 63, nt = (s >> 9) & 15, ks = s >> 13;
        int n = nt * 16 + (lane & 15);
        int k = ks * 32 + ((lane >> 4) << 3) + j;
        float v0, v1;
        if (k < 128) { v0 = W1l[n * 128 + k];       v1 = W1l[n * 128 + k + 1]; }
        else         { v0 = W1r[n * 128 + k - 128]; v1 = W1r[n * 128 + k - 127]; }
        Wf1[i] = (unsigned)f2bf(v0) | ((unsigned)f2bf(v1) << 16);
    } else {
        int i = (b - SCAN_NB - 128) * 256 + t;    // < 16384 u32
        int s = i * 2;
        int j = s & 7, lane = (s >> 3) & 63, nt = (s >> 9) & 7, ks = s >> 12;
        int n = nt * 16 + (lane & 15);
        int k = ks * 32 + ((lane >> 4) << 3) + j;
        float v0, v1;
        if (n < 64) { v0 = W2l[n * 256 + k];        v1 = W2l[n * 256 + k + 1]; }
        else        { v0 = W2r[(n - 64) * 256 + k]; v1 = W2r[(n - 64) * 256 + k + 1]; }
        Wf2[i] = (unsigned)f2bf(v0) | ((unsigned)f2bf(v1) << 16);
    }
}

// ---------------- rank (atomic count w/ rank) | convert_x -- grid-stride fused ----------------
__global__ __launch_bounds__(256) void rank_convert_k(const int* __restrict__ dst,
                                                      int* __restrict__ cnt,
                                                      int* __restrict__ rank,
                                                      const float* __restrict__ x,
                                                      unsigned int* __restrict__ A1u) {
    int b = blockIdx.x, t = threadIdx.x;
    if (b < RANK_NB) {
        const int T = RANK_NB * 256;
        for (int e = b * 256 + t; e < N_EDGES; e += T)
            rank[e] = atomicAdd(&cnt[dst[e]], 1);
    } else {
        const int T = CONV_NB * 256;
        for (int i = (b - RANK_NB) * 256 + t; i < N_NODES * 64; i += T) {
            int n = i >> 6, p = i & 63;
            float2 v = ((const float2*)(x + (size_t)n * IN_FEAT))[p];
            A1u[(size_t)n * 128 + 64 + p] = (unsigned)f2bf(v.x) | ((unsigned)f2bf(v.y) << 16);
        }
    }
}

// ---------------- scan phase A: per-block sums of cnt ----------------
__global__ __launch_bounds__(256) void bsum_k(const int* __restrict__ cnt,
                                              int* __restrict__ bsum) {
    int i = blockIdx.x * 256 + threadIdx.x;
    int v = (i < N_NODES) ? cnt[i] : 0;
#pragma unroll
    for (int m = 1; m < 64; m <<= 1) v += __shfl_xor(v, m);
    __shared__ int ws4[4];
    if ((threadIdx.x & 63) == 0) ws4[threadIdx.x >> 6] = v;
    __syncthreads();
    if (threadIdx.x == 0) bsum[blockIdx.x] = ws4[0] + ws4[1] + ws4[2] + ws4[3];
}

// ---------------- scan phase B: exclusive scan of block sums (1 block) ----------------
__global__ __launch_bounds__(256) void bscan_k(const int* __restrict__ bsum,
                                               int* __restrict__ boff) {
    __shared__ int s[256];
    int t = threadIdx.x;
    int v = (t < SCAN_NB) ? bsum[t] : 0;
    s[t] = v;
    __syncthreads();
    for (int off = 1; off < 256; off <<= 1) {
        int add = (t >= off) ? s[t - off] : 0;
        __syncthreads();
        s[t] += add;
        __syncthreads();
    }
    if (t < SCAN_NB) boff[t] = s[t] - v;   // exclusive
}

// ---------------- scan phase C: per-block exclusive scan + offset -> rowptr ----------------
__global__ __launch_bounds__(256) void rowptr_k(const int* __restrict__ cnt,
                                                const int* __restrict__ boff,
                                                int* __restrict__ rowptr) {
    __shared__ int s[256];
    int t = threadIdx.x;
    int i = blockIdx.x * 256 + t;
    int v = (i < N_NODES) ? cnt[i] : 0;
    s[t] = v;
    __syncthreads();
    for (int off = 1; off < 256; off <<= 1) {
        int add = (t >= off) ? s[t - off] : 0;
        __syncthreads();
        s[t] += add;
        __syncthreads();
    }
    if (i < N_NODES) rowptr[i] = boff[blockIdx.x] + s[t] - v;
    if (blockIdx.x == 0 && t == 0) rowptr[N_NODES] = N_EDGES;
}

// ---------------- CSR fill: no atomics (rank precomputed), grid-stride ----------------
__global__ __launch_bounds__(256) void fill_k(const int* __restrict__ src,
                                              const int* __restrict__ dst,
                                              const int* __restrict__ rowptr,
                                              const int* __restrict__ rank,
                                              int* __restrict__ eids) {
    const int T = FILL_NB * 256;
    for (int e = blockIdx.x * 256 + threadIdx.x; e < N_EDGES; e += T) {
        int d = dst[e];
        eids[rowptr[d] + rank[e]] = src[e];
    }
}

// ---------------- gather-mean layer 1: 4 edges/iter, dwordx4/lane, grid-stride ----------------
__global__ __launch_bounds__(256) void gather1_k(const unsigned int* __restrict__ Au,
                                                 const int* __restrict__ eids,
                                                 const int* __restrict__ rowptr,
                                                 unsigned int* __restrict__ Aw) {
    int w = threadIdx.x >> 6, lane = threadIdx.x & 63;
    int eg = lane >> 4, cq = lane & 15;
    for (int g = blockIdx.x; g < NGROUPS; g += GATH_NB) {
        int node = g * 4 + w;
        int b = rowptr[node], e = rowptr[node + 1];
        float a0 = 0.f, a1 = 0.f, a2 = 0.f, a3 = 0.f, a4 = 0.f, a5 = 0.f, a6 = 0.f, a7 = 0.f;
        for (int i = b + eg; i < e; i += 4) {
            int s = eids[i];
            uint4 v = ((const uint4*)(Au + (size_t)s * 128 + 64))[cq];
            a0 += bflo(v.x); a1 += bfhi(v.x);
            a2 += bflo(v.y); a3 += bfhi(v.y);
            a4 += bflo(v.z); a5 += bfhi(v.z);
            a6 += bflo(v.w); a7 += bfhi(v.w);
        }
#pragma unroll
        for (int m = 16; m <= 32; m <<= 1) {
            a0 += __shfl_xor(a0, m); a1 += __shfl_xor(a1, m);
            a2 += __shfl_xor(a2, m); a3 += __shfl_xor(a3, m);
            a4 += __shfl_xor(a4, m); a5 += __shfl_xor(a5, m);
            a6 += __shfl_xor(a6, m); a7 += __shfl_xor(a7, m);
        }
        if (eg == 0) {
            int deg = e - b; if (deg < 1) deg = 1;
            float inv = 1.f / (float)deg;
            uint4 r;
            r.x = (unsigned)f2bf(a0 * inv) | ((unsigned)f2bf(a1 * inv) << 16);
            r.y = (unsigned)f2bf(a2 * inv) | ((unsigned)f2bf(a3 * inv) << 16);
            r.z = (unsigned)f2bf(a4 * inv) | ((unsigned)f2bf(a5 * inv) << 16);
            r.w = (unsigned)f2bf(a6 * inv) | ((unsigned)f2bf(a7 * inv) << 16);
            ((uint4*)(Aw + (size_t)node * 128))[cq] = r;
        }
    }
}

// ---------------- MFMA GEMM1: h = relu(A1 @ W1cat^T + b1), M=M_PAD N=256 K=256 ----------------
__global__ __launch_bounds__(256) void mfma_gemm1_k(
        const unsigned short* __restrict__ A, const unsigned short* __restrict__ Wf,
        const float* __restrict__ b1, unsigned short* __restrict__ h) {
    int wv = threadIdx.x >> 6, lane = threadIdx.x & 63;
    int rowh = wv >> 1, colh = wv & 1;
    int m0 = blockIdx.x * 64 + rowh * 32;
    int row = lane & 15, kg = lane >> 4;
    const short8* Wf8 = (const short8*)Wf;

    short8 af[2][8];
#pragma unroll
    for (int mt = 0; mt < 2; mt++) {
        const short8* ar = (const short8*)(A + (size_t)(m0 + mt * 16 + row) * 256 + kg * 8);
#pragma unroll
        for (int ks = 0; ks < 8; ks++) af[mt][ks] = ar[ks * 4];
    }
    f32x4 acc[2][8];
#pragma unroll
    for (int mt = 0; mt < 2; mt++)
#pragma unroll
        for (int nt = 0; nt < 8; nt++) acc[mt][nt] = (f32x4)(0.f);

#pragma unroll
    for (int ks = 0; ks < 8; ks++) {
        short8 bf[8];
#pragma unroll
        for (int nt = 0; nt < 8; nt++)
            bf[nt] = Wf8[(ks * 16 + colh * 8 + nt) * 64 + lane];
#pragma unroll
        for (int nt = 0; nt < 8; nt++) {
#pragma unroll
            for (int mt = 0; mt < 2; mt++)
                acc[mt][nt] = __builtin_amdgcn_mfma_f32_16x16x32_bf16(af[mt][ks], bf[nt],
                                                                      acc[mt][nt], 0, 0, 0);
        }
    }

#pragma unroll
    for (int mt = 0; mt < 2; mt++) {
        int r0 = m0 + mt * 16 + kg * 4;
#pragma unroll
        for (int nt = 0; nt < 8; nt++) {
            int c = colh * 128 + nt * 16 + row;
            float bias = b1[c];
#pragma unroll
            for (int i = 0; i < 4; i++) {
                float v = acc[mt][nt][i] + bias;
                v = v > 0.f ? v : 0.f;
                h[(size_t)(r0 + i) * 256 + c] = f2bf(v);
            }
        }
    }
}

// ---------------- MFMA GEMM2: [y | out_r] = h @ W2cat^T, M=M_PAD N=128 K=256 ----------------
__global__ __launch_bounds__(256) void mfma_gemm2_k(
        const unsigned short* __restrict__ A, const unsigned short* __restrict__ Wf,
        const float* __restrict__ b2, unsigned short* __restrict__ y,
        float* __restrict__ out) {
    int wv = threadIdx.x >> 6, lane = threadIdx.x & 63;
    int m0 = blockIdx.x * 128 + wv * 32;
    int row = lane & 15, kg = lane >> 4;
    const short8* Wf8 = (const short8*)Wf;

    short8 af[2][8];
#pragma unroll
    for (int mt = 0; mt < 2; mt++) {
        const short8* ar = (const short8*)(A + (size_t)(m0 + mt * 16 + row) * 256 + kg * 8);
#pragma unroll
        for (int ks = 0; ks < 8; ks++) af[mt][ks] = ar[ks * 4];
    }
    f32x4 acc[2][8];
#pragma unroll
    for (int mt = 0; mt < 2; mt++)
#pragma unroll
        for (int nt = 0; nt < 8; nt++) acc[mt][nt] = (f32x4)(0.f);

#pragma unroll
    for (int ks = 0; ks < 8; ks++) {
        short8 bf[8];
#pragma unroll
        for (int nt = 0; nt < 8; nt++)
            bf[nt] = Wf8[(ks * 8 + nt) * 64 + lane];
#pragma unroll
        for (int nt = 0; nt < 8; nt++) {
#pragma unroll
            for (int mt = 0; mt < 2; mt++)
                acc[mt][nt] = __builtin_amdgcn_mfma_f32_16x16x32_bf16(af[mt][ks], bf[nt],
                                                                      acc[mt][nt], 0, 0, 0);
        }
    }

#pragma unroll
    for (int mt = 0; mt < 2; mt++) {
        int r0 = m0 + mt * 16 + kg * 4;
#pragma unroll
        for (int nt = 0; nt < 8; nt++) {
            int c = nt * 16 + row;   // 0..127
#pragma unroll
            for (int i = 0; i < 4; i++) {
                int rr = r0 + i;
                if (nt < 4) {
                    y[(size_t)rr * OUT_F + c] = f2bf(acc[mt][nt][i]);
                } else if (rr < N_NODES) {
                    out[(size_t)rr * OUT_F + (c - 64)] = acc[mt][nt][i] + b2[c - 64];
                }
            }
        }
    }
}

// ---------------- gather-mean layer 2: 8 edges/iter, dwordx4/lane, grid-stride ----------------
__global__ __launch_bounds__(256) void gather2_k(const unsigned int* __restrict__ yu,
                                                 const int* __restrict__ eids,
                                                 const int* __restrict__ rowptr,
                                                 float* __restrict__ out) {
    int w = threadIdx.x >> 6, lane = threadIdx.x & 63;
    int eg = lane >> 3, cq = lane & 7;
    for (int g = blockIdx.x; g < NGROUPS; g += GATH_NB) {
        int node = g * 4 + w;
        int b = rowptr[node], e = rowptr[node + 1];
        float a0 = 0.f, a1 = 0.f, a2 = 0.f, a3 = 0.f, a4 = 0.f, a5 = 0.f, a6 = 0.f, a7 = 0.f;
        for (int i = b + eg; i < e; i += 8) {
            int s = eids[i];
            uint4 v = ((const uint4*)(yu + (size_t)s * 32))[cq];
            a0 += bflo(v.x); a1 += bfhi(v.x);
            a2 += bflo(v.y); a3 += bfhi(v.y);
            a4 += bflo(v.z); a5 += bfhi(v.z);
            a6 += bflo(v.w); a7 += bfhi(v.w);
        }
#pragma unroll
        for (int m = 8; m <= 32; m <<= 1) {
            a0 += __shfl_xor(a0, m); a1 += __shfl_xor(a1, m);
            a2 += __shfl_xor(a2, m); a3 += __shfl_xor(a3, m);
            a4 += __shfl_xor(a4, m); a5 += __shfl_xor(a5, m);
            a6 += __shfl_xor(a6, m); a7 += __shfl_xor(a7, m);
        }
        if (eg == 0) {
            int deg = e - b; if (deg < 1) deg = 1;
            float inv = 1.f / (float)deg;
            float4* p = (float4*)(out + (size_t)node * OUT_F + cq * 8);
            float4 c0 = p[0], c1 = p[1];
            c0.x += a0 * inv; c0.y += a1 * inv; c0.z += a2 * inv; c0.w += a3 * inv;
            c1.x += a4 * inv; c1.y += a5 * inv; c1.z += a6 * inv; c1.w += a7 * inv;
            p[0] = c0; p[1] = c1;
        }
    }
}

extern "C" void kernel_launch(void* const* d_in, const int* in_sizes, int n_in,
                              void* d_out, int out_size, void* d_ws, size_t ws_size,
                              hipStream_t stream) {
    const float* x    = (const float*)d_in[0];
    const int*   eidx = (const int*)d_in[1];
    const float* W1l  = (const float*)d_in[2];
    const float* W1r  = (const float*)d_in[3];
    const float* b1   = (const float*)d_in[4];
    const float* W2l  = (const float*)d_in[5];
    const float* W2r  = (const float*)d_in[6];
    const float* b2   = (const float*)d_in[7];
    float* out = (float*)d_out;

    const int* src = eidx;             // edge_index[0]
    const int* dst = eidx + N_EDGES;   // edge_index[1]

    // workspace layout (ushort units)
    unsigned short* A1   = (unsigned short*)d_ws;              // [M_PAD][256] bf16
    unsigned short* hbuf = A1 + (size_t)M_PAD * 256;           // [M_PAD][256] bf16
    unsigned short* ybuf = hbuf + (size_t)M_PAD * 256;         // [M_PAD][64]  bf16
    unsigned short* W1f  = ybuf + (size_t)M_PAD * OUT_F;       // 65536 (frag layout)
    unsigned short* W2f  = W1f + 65536;                        // 32768 (frag layout)
    int* cnt    = (int*)(W2f + 32768);            // 50000
    int* rowptr = cnt + N_NODES;                  // 50001
    int* eids   = rowptr + N_NODES + 1;           // 800000
    int* rank   = eids + N_EDGES;                 // 800000
    int* bsum   = rank + N_EDGES;                 // 196
    int* boff   = bsum + SCAN_NB;                 // 196

    // prep: zero cnt | convert weights to fragment layout
    prep_k<<<SCAN_NB + 128 + 64, 256, 0, stream>>>(cnt, W1l, W1r, (unsigned int*)W1f,
                                                   W2l, W2r, (unsigned int*)W2f);

    // rank (atomic degree count w/ per-edge rank) fused with x->bf16 convert, grid-stride
    rank_convert_k<<<RANK_NB + CONV_NB, 256, 0, stream>>>(dst, cnt, rank, x,
                                                          (unsigned int*)A1);

    // rowptr scan (3-phase)
    bsum_k<<<SCAN_NB, 256, 0, stream>>>(cnt, bsum);
    bscan_k<<<1, 256, 0, stream>>>(bsum, boff);
    rowptr_k<<<SCAN_NB, 256, 0, stream>>>(cnt, boff, rowptr);

    // CSR fill (atomic-free, grid-stride)
    fill_k<<<FILL_NB, 256, 0, stream>>>(src, dst, rowptr, rank, eids);

    // layer-1 aggregation (gather-mean, 4 edges/iter, grid-stride)
    gather1_k<<<GATH_NB, 256, 0, stream>>>((const unsigned int*)A1, eids, rowptr,
                                           (unsigned int*)A1);

    // GEMM1 -> h (bf16)
    mfma_gemm1_k<<<M_PAD / 64, 256, 0, stream>>>(A1, W1f, b1, hbuf);

    // GEMM2 -> y (bf16), out_r + b2 (fp32)
    mfma_gemm2_k<<<M_PAD / 128, 256, 0, stream>>>(hbuf, W2f, b2, ybuf, out);

    // layer-2 aggregation (gather-mean, 8 edges/iter, grid-stride)
    gather2_k<<<GATH_NB, 256, 0, stream>>>((const unsigned int*)ybuf, eids, rowptr, out);
}